// Round 9
// baseline (67.326 us; speedup 1.0000x reference)
//
#include <hip/hip_runtime.h>
#include <math.h>

// DiscriminativeLoss: N=1e6 x D=32 fp32, K=64, scalar out.
// R9 (on R8 base, 65.8us):
// (a) pass1: 512-thr blocks, thread=(cluster k, sub 0..7) -> one 16B load
//     covers a full 128B row per 8-lane group; divergence max/mean 1.45->1.36;
//     part1 write becomes outp[tid] (perfect coalescing); unroll x4.
// (b) pass2: grid-stride unrolled x2 -> 16 independent loads in flight/lane;
//     split d2 accumulator pair for FMA-chain ILP.
// Kept lessons: no volume global atomics (R5: write-through to HBM), no
// same-line returning-atomic tails (R6: ~80cyc serialized each), per-cluster
// register walk beats equal-work walk (R6).

#define EPS_F 1e-8f
constexpr int D = 32;
constexpr int K = 64;
constexpr int NPTS = 1024;               // points per pass1 block
constexpr int P1 = K * D + K;            // 2112: 2048 sums + 64 counts
constexpr int NCH = 64;                  // reduction chunks
constexpr int NBLK2 = 2048;              // pass2 blocks
constexpr int MPAD = 40;                 // LDS means row stride

// ---------------- pass 1: sort-by-label, 8-lane-row register sums ----------
__global__ __launch_bounds__(512) void pass1_kernel(
    const float* __restrict__ feat, const int* __restrict__ lab,
    float* __restrict__ part1, int N)
{
    __shared__ int            s_lab[NPTS];
    __shared__ unsigned short s_idx[NPTS];
    __shared__ int            s_hist[K];
    __shared__ int            s_pref[K];
    __shared__ int            s_cur[K];

    const int tid = threadIdx.x;
    const long long base = (long long)blockIdx.x * NPTS;
    int npts = (int)((long long)N - base);
    if (npts > NPTS) npts = NPTS;

    if (tid < K) s_hist[tid] = 0;
    __syncthreads();

    // stage labels (int2, 512 thr cover 1024 pts) + histogram
    const int n2 = npts >> 1;
    for (int i2 = tid; i2 < n2; i2 += 512) {
        const int2 v = ((const int2*)(lab + base))[i2];
        s_lab[i2 * 2 + 0] = v.x; s_lab[i2 * 2 + 1] = v.y;
        atomicAdd(&s_hist[v.x], 1); atomicAdd(&s_hist[v.y], 1);
    }
    for (int i = (n2 << 1) + tid; i < npts; i += 512) {  // odd tail
        const int l = lab[base + i];
        s_lab[i] = l;
        atomicAdd(&s_hist[l], 1);
    }
    __syncthreads();

    // exclusive prefix over 64 bins (wave 0)
    if (tid < 64) {
        const int h = s_hist[tid];
        int v = h;
        for (int off = 1; off < 64; off <<= 1) {
            const int up = __shfl_up(v, off);
            if (tid >= off) v += up;
        }
        s_pref[tid] = v - h;
        s_cur[tid]  = v - h;
    }
    __syncthreads();

    // scatter sorted indices (1 int atomic per point)
    for (int i = tid; i < npts; i += 512) {
        const int l = s_lab[i];
        const int pos = atomicAdd(&s_cur[l], 1);
        s_idx[pos] = (unsigned short)i;
    }
    __syncthreads();

    // register accumulation: thread = (cluster k = tid>>3, sub = tid&7);
    // 8 lanes cover one 128B row per iteration -> 1 float4 load per lane.
    const int k = tid >> 3, sub = tid & 7;
    const int start = s_pref[k], len = s_hist[k];
    float4 a = {0.f, 0.f, 0.f, 0.f};
    int i = 0;
    for (; i + 4 <= len; i += 4) {            // unroll x4: 4 loads in flight
        const int i0 = s_idx[start + i + 0];
        const int i1 = s_idx[start + i + 1];
        const int i2 = s_idx[start + i + 2];
        const int i3 = s_idx[start + i + 3];
        const float4 x0 = *(const float4*)(feat + (base + i0) * D + sub * 4);
        const float4 x1 = *(const float4*)(feat + (base + i1) * D + sub * 4);
        const float4 x2 = *(const float4*)(feat + (base + i2) * D + sub * 4);
        const float4 x3 = *(const float4*)(feat + (base + i3) * D + sub * 4);
        a.x += (x0.x + x1.x) + (x2.x + x3.x);
        a.y += (x0.y + x1.y) + (x2.y + x3.y);
        a.z += (x0.z + x1.z) + (x2.z + x3.z);
        a.w += (x0.w + x1.w) + (x2.w + x3.w);
    }
    for (; i < len; ++i) {
        const int i0 = s_idx[start + i];
        const float4 x0 = *(const float4*)(feat + (base + i0) * D + sub * 4);
        a.x += x0.x; a.y += x0.y; a.z += x0.z; a.w += x0.w;
    }
    float* outp = part1 + (long long)blockIdx.x * P1;
    ((float4*)outp)[tid] = a;                 // cell k*32+sub*4 == float4 tid
    if (tid < K) outp[K * D + tid] = (float)s_hist[tid];
}

// ---------------- stage A: nblk1 partials -> NCH partials (coalesced) ------
__global__ __launch_bounds__(256) void reduce1_kernel(
    const float* __restrict__ part1, float* __restrict__ part2,
    int chsz, int nblk1)
{
    const int e = blockIdx.x * 256 + threadIdx.x;
    if (e >= P1) return;
    const int y = blockIdx.y;
    const int b0 = y * chsz;
    int b1 = b0 + chsz; if (b1 > nblk1) b1 = nblk1;
    float s = 0.f;
    for (int b = b0; b < b1; b++) s += part1[(long long)b * P1 + e];
    part2[(long long)y * P1 + e] = s;
}

// ---------------- stage B: NCH partials -> means, inv_counts ---------------
__global__ __launch_bounds__(256) void mean_kernel(
    const float* __restrict__ part2,
    float* __restrict__ means, float* __restrict__ icnt)
{
    const int e = blockIdx.x * blockDim.x + threadIdx.x;
    if (e >= P1) return;
    if (e < K * D) {
        float s = 0.f, c = 0.f;
        const int k = e >> 5;
        for (int y = 0; y < NCH; y++) {
            s += part2[(long long)y * P1 + e];
            c += part2[(long long)y * P1 + K * D + k];
        }
        means[e] = s / fmaxf(c, 1.0f);
    } else {
        float s = 0.f;
        for (int y = 0; y < NCH; y++) s += part2[(long long)y * P1 + e];
        icnt[e - K * D] = 1.0f / fmaxf(s, 1.0f);
    }
}

// ---------------- pass 2: lane-owns-point x2-stream + block0 inter/reg -----
__global__ __launch_bounds__(256) void pass2_kernel(
    const float* __restrict__ feat, const int* __restrict__ lab,
    const float* __restrict__ means, const float* __restrict__ icnt,
    float* __restrict__ hpart, float* __restrict__ ir, int N)
{
    __shared__ float s_m[K * MPAD];   // padded means, 10 KB
    __shared__ float s_ic[K];
    __shared__ float s_red[256];
    const int tid = threadIdx.x;

    for (int e = tid; e < K * D; e += 256)
        s_m[(e >> 5) * MPAD + (e & 31)] = means[e];
    if (tid < K) s_ic[tid] = icnt[tid];
    __syncthreads();

    float racc = 0.f;
    const long long PSTRIDE = (long long)NBLK2 * 256;
    for (long long p = (long long)blockIdx.x * 256 + tid; p < N; p += 2 * PSTRIDE) {
        const long long pB = p + PSTRIDE;
        const bool vB = (pB < N);
        const int la = lab[p];
        const int lb = vB ? lab[pB] : 0;
        const float4* frA = (const float4*)(feat + p * D);
        const float4* frB = (const float4*)(feat + pB * D);
        float4 fa[8], fb[8];
        #pragma unroll
        for (int j = 0; j < 8; j++) fa[j] = frA[j];    // 8 loads in flight
        if (vB) {
            #pragma unroll
            for (int j = 0; j < 8; j++) fb[j] = frB[j];// +8 more
        }
        const float* mrA = s_m + la * MPAD;
        float d2a0 = 0.f, d2a1 = 0.f;
        #pragma unroll
        for (int j = 0; j < 8; j += 2) {
            const float4 m0 = *(const float4*)(mrA + j * 4);
            const float4 m1 = *(const float4*)(mrA + j * 4 + 4);
            const float ax = fa[j].x - m0.x + EPS_F, ay = fa[j].y - m0.y + EPS_F;
            const float az = fa[j].z - m0.z + EPS_F, aw = fa[j].w - m0.w + EPS_F;
            const float bx = fa[j+1].x - m1.x + EPS_F, by = fa[j+1].y - m1.y + EPS_F;
            const float bz = fa[j+1].z - m1.z + EPS_F, bw = fa[j+1].w - m1.w + EPS_F;
            d2a0 += ax * ax + ay * ay + az * az + aw * aw;
            d2a1 += bx * bx + by * by + bz * bz + bw * bw;
        }
        const float hA = fmaxf(sqrtf(d2a0 + d2a1) - 1.5f, 0.f);
        racc += hA * hA * s_ic[la];
        if (vB) {
            const float* mrB = s_m + lb * MPAD;
            float d2b0 = 0.f, d2b1 = 0.f;
            #pragma unroll
            for (int j = 0; j < 8; j += 2) {
                const float4 m0 = *(const float4*)(mrB + j * 4);
                const float4 m1 = *(const float4*)(mrB + j * 4 + 4);
                const float ax = fb[j].x - m0.x + EPS_F, ay = fb[j].y - m0.y + EPS_F;
                const float az = fb[j].z - m0.z + EPS_F, aw = fb[j].w - m0.w + EPS_F;
                const float bx = fb[j+1].x - m1.x + EPS_F, by = fb[j+1].y - m1.y + EPS_F;
                const float bz = fb[j+1].z - m1.z + EPS_F, bw = fb[j+1].w - m1.w + EPS_F;
                d2b0 += ax * ax + ay * ay + az * az + aw * aw;
                d2b1 += bx * bx + by * by + bz * bz + bw * bw;
            }
            const float hB = fmaxf(sqrtf(d2b0 + d2b1) - 1.5f, 0.f);
            racc += hB * hB * s_ic[lb];
        }
    }
    s_red[tid] = racc;
    __syncthreads();
    for (int st = 128; st; st >>= 1) { if (tid < st) s_red[tid] += s_red[tid + st]; __syncthreads(); }
    if (tid == 0) hpart[blockIdx.x] = s_red[0];

    if (blockIdx.x != 0) return;
    // ---- block 0 epilogue: inter + reg from s_m (overlaps other blocks) ----
    __syncthreads();
    float mj[32];
    const int j = tid & 63;
    #pragma unroll
    for (int d = 0; d < 32; d++) mj[d] = s_m[j * MPAD + d];
    float isum = 0.f;
    const int igrp = tid >> 6;        // 0..3, 16 i's each; i wave-uniform
    for (int ii = 0; ii < 16; ii++) {
        const int i = igrp * 16 + ii;
        const float4* srow = (const float4*)(s_m + i * MPAD);
        float d2 = 0.f;
        #pragma unroll
        for (int q = 0; q < 8; q++) {
            const float4 mv = srow[q];
            const float b0 = mv.x - mj[q * 4 + 0] + EPS_F;
            const float b1 = mv.y - mj[q * 4 + 1] + EPS_F;
            const float b2 = mv.z - mj[q * 4 + 2] + EPS_F;
            const float b3 = mv.w - mj[q * 4 + 3] + EPS_F;
            d2 += b0 * b0 + b1 * b1 + b2 * b2 + b3 * b3;
        }
        if (i != j) {
            const float h = fmaxf(1.0f - sqrtf(d2), 0.f);  // 2*margin - pd
            isum += h * h;
        }
    }
    s_red[tid] = isum;
    __syncthreads();
    for (int st = 128; st; st >>= 1) { if (tid < st) s_red[tid] += s_red[tid + st]; __syncthreads(); }
    if (tid == 0) ir[0] = s_red[0] * (1.0f / ((K - 1) * K));
    __syncthreads();

    float r = 0.f;
    if (tid < 64) {
        float d2 = 0.f;
        #pragma unroll
        for (int d = 0; d < 32; d++) { const float t = mj[d] + EPS_F; d2 += t * t; }
        r = sqrtf(d2);
    }
    s_red[tid] = r;
    __syncthreads();
    for (int st = 128; st; st >>= 1) { if (tid < st) s_red[tid] += s_red[tid + st]; __syncthreads(); }
    if (tid == 0) ir[1] = s_red[0] * (1.0f / K);
}

// ---------------- final: hpart sum + combine --------------------------------
__global__ __launch_bounds__(256) void final_kernel(
    const float* __restrict__ hpart, const float* __restrict__ ir,
    float* __restrict__ out)
{
    __shared__ float s_red[256];
    const int tid = threadIdx.x;
    float hs = 0.f;
    for (int b = tid; b < NBLK2; b += 256) hs += hpart[b];
    s_red[tid] = hs;
    __syncthreads();
    for (int st = 128; st; st >>= 1) { if (tid < st) s_red[tid] += s_red[tid + st]; __syncthreads(); }
    if (tid == 0) out[0] = s_red[0] * (1.0f / K) + ir[0] + 0.001f * ir[1];
}

extern "C" void kernel_launch(void* const* d_in, const int* in_sizes, int n_in,
                              void* d_out, int out_size, void* d_ws, size_t ws_size,
                              hipStream_t stream)
{
    const float* feat = (const float*)d_in[0];
    const int*   lab  = (const int*)d_in[1];
    const int N = in_sizes[1];            // 1e6; D=32, K=64 fixed by reference

    float* ws = (float*)d_ws;

    const int nblk1 = (N + NPTS - 1) / NPTS;         // 977
    const int chsz  = (nblk1 + NCH - 1) / NCH;       // 16

    float* means = ws;                               // K*D
    float* icnt  = means + K * D;                    // K
    float* ir    = icnt + K;                         // 2 (+pad 2)
    float* part2 = ir + 4;                           // NCH*P1
    float* hpart = part2 + (long long)NCH * P1;      // NBLK2
    float* part1 = hpart + NBLK2;                    // nblk1*P1

    pass1_kernel<<<nblk1, 512, 0, stream>>>(feat, lab, part1, N);
    reduce1_kernel<<<dim3((P1 + 255) / 256, NCH), 256, 0, stream>>>(part1, part2, chsz, nblk1);
    mean_kernel<<<(P1 + 255) / 256, 256, 0, stream>>>(part2, means, icnt);
    pass2_kernel<<<NBLK2, 256, 0, stream>>>(feat, lab, means, icnt, hpart, ir, N);
    final_kernel<<<1, 256, 0, stream>>>(hpart, ir, (float*)d_out);
}